// Round 1
// baseline (655.055 us; speedup 1.0000x reference)
//
#include <hip/hip_runtime.h>

#define HID 32
#define NODE_DIM 8

// ---------------------------------------------------------------------------
// Edge kernel: one edge per wave (64 lanes).
//   lane = (g, o): o = lane&31 output index, g = lane>>5 selects k-half.
//   W2 slice [g*16 .. g*16+15][i=0..7][o] register-cached per lane (128 VGPR).
//   msg[o] = sum_i x_i*b2[i*32+o] + sum_k h_k * (sum_i x_i * W2[k, i*32+o])
//   scatter: atomicAdd into s[dst*32+o], count into cnt[dst].
// ---------------------------------------------------------------------------
__global__ __launch_bounds__(256, 2)
void edge_kernel(const float* __restrict__ x,
                 const float* __restrict__ ea,
                 const int* __restrict__ eidx,
                 const float* __restrict__ W1, const float* __restrict__ b1,
                 const float* __restrict__ W2, const float* __restrict__ b2,
                 float* __restrict__ s, int* __restrict__ cnt,
                 int E)
{
    const int tid   = blockIdx.x * blockDim.x + threadIdx.x;
    const int lane  = threadIdx.x & 63;
    const int o     = lane & 31;
    const int g     = lane >> 5;
    const int wave  = tid >> 6;
    const int nwav  = (gridDim.x * blockDim.x) >> 6;

    // Register-cache W2 slice for this lane's (g, o).
    float w2r[16][8];
#pragma unroll
    for (int kp = 0; kp < 16; ++kp) {
        const float* wrow = W2 + (size_t)(g * 16 + kp) * (NODE_DIM * HID) + o;
#pragma unroll
        for (int i = 0; i < 8; ++i) w2r[kp][i] = wrow[i * 32];
    }
    float b2r[8];
#pragma unroll
    for (int i = 0; i < 8; ++i) b2r[i] = b2[i * 32 + o];

    // W1 column for k = o (h is computed redundantly in both halves).
    const float w10 = W1[o], w11 = W1[32 + o], w12 = W1[64 + o], b1r = b1[o];

    for (int e = wave; e < E; e += nwav) {
        const int src = eidx[e];
        const int dst = eidx[E + e];
        const float ea0 = ea[e * 3 + 0];
        const float ea1 = ea[e * 3 + 1];
        const float ea2 = ea[e * 3 + 2];

        const float4 xa = *(const float4*)(x + (size_t)src * 8);
        const float4 xb = *(const float4*)(x + (size_t)src * 8 + 4);
        const float xv[8] = {xa.x, xa.y, xa.z, xa.w, xb.x, xb.y, xb.z, xb.w};

        float z = b1r + ea0 * w10 + ea1 * w11 + ea2 * w12;
        float h = z > 0.f ? z : 0.f;

        // b2 contribution (counted once -> only in g==0 partial)
        float tb = 0.f;
#pragma unroll
        for (int i = 0; i < 8; ++i) tb += xv[i] * b2r[i];
        float acc = (g == 0) ? tb : 0.f;

#pragma unroll
        for (int kp = 0; kp < 16; ++kp) {
            const float hk = __shfl(h, (g << 4) + kp, 32);  // h[g*16+kp]
            float t = 0.f;
#pragma unroll
            for (int i = 0; i < 8; ++i) t += xv[i] * w2r[kp][i];
            acc += hk * t;
        }

        const float other = __shfl_xor(acc, 32, 64);  // combine the two k-halves
        acc += other;

        if (g == 0) atomicAdd(&s[(size_t)dst * 32 + o], acc);
        if (lane == 0) atomicAdd(&cnt[dst], 1);
    }
}

// ---------------------------------------------------------------------------
// Node kernel: h_node = relu(x @ root + s/max(cnt,1) + conv_bias), in-place on s.
// ---------------------------------------------------------------------------
__global__ __launch_bounds__(256)
void node_kernel(const float* __restrict__ x,
                 const float* __restrict__ root,
                 const float* __restrict__ conv_bias,
                 float* __restrict__ s, const int* __restrict__ cnt,
                 int N)
{
    const int idx = blockIdx.x * blockDim.x + threadIdx.x;
    if (idx >= N * 32) return;
    const int n = idx >> 5, o = idx & 31;
    const float c = (float)(cnt[n] > 1 ? cnt[n] : 1);
    float v = s[idx] / c + conv_bias[o];
    const float* xr = x + (size_t)n * 8;
#pragma unroll
    for (int i = 0; i < 8; ++i) v += xr[i] * root[i * 32 + o];
    s[idx] = v > 0.f ? v : 0.f;
}

// ---------------------------------------------------------------------------
// Per-graph pooling (batch is sorted -> binary search for segment) + MLP head.
// One block of 128 threads per graph.
// ---------------------------------------------------------------------------
__global__ __launch_bounds__(128)
void pool_mlp_kernel(const float* __restrict__ hnode,
                     const int* __restrict__ batch,
                     const float* __restrict__ ratios,
                     const int* __restrict__ ids,
                     const float* __restrict__ emb,
                     const float* __restrict__ fc0w, const float* __restrict__ fc0b,
                     const float* __restrict__ fc1w, const float* __restrict__ fc1b,
                     const float* __restrict__ fc2w, const float* __restrict__ fc2b,
                     float* __restrict__ out, int N)
{
    __shared__ float zs[96];
    __shared__ float z1[64];
    __shared__ float red[128];
    __shared__ int seg[2];

    const int g = blockIdx.x;
    const int t = threadIdx.x;

    if (t < 2) {
        const int target = g + t;
        int lo = 0, hi = N;
        while (lo < hi) {
            const int mid = (lo + hi) >> 1;
            if (batch[mid] < target) lo = mid + 1; else hi = mid;
        }
        seg[t] = lo;
    }
    __syncthreads();
    const int start = seg[0], end = seg[1];

    // pooled sum: 4 node-chunks x 32 dims
    const int o = t & 31, chunk = t >> 5;
    float sum = 0.f;
    for (int n = start + chunk; n < end; n += 4) sum += hnode[(size_t)n * 32 + o];
    red[t] = sum;
    __syncthreads();

    if (t < 32) {
        const float p = red[t] + red[t + 32] + red[t + 64] + red[t + 96];
        float c = (float)(end - start);
        if (c < 1.f) c = 1.f;
        zs[t] = p / c;
    }
    if (t >= 32 && t < 96) {
        const int j = t - 32;  // u index 0..63
        float u = 0.f;
#pragma unroll
        for (int r = 0; r < 5; ++r) u += ratios[r] * emb[(size_t)ids[r] * 64 + j];
        zs[32 + j] = u;
    }
    __syncthreads();

    if (t < 64) {
        float a = fc0b[t];
        for (int k = 0; k < 96; ++k) a += zs[k] * fc0w[k * 64 + t];
        z1[t] = a > 0.f ? a : 0.f;
    }
    __syncthreads();

    if (t < 32) {
        float a = fc1b[t];
        for (int k = 0; k < 64; ++k) a += z1[k] * fc1w[k * 32 + t];
        red[t] = a > 0.f ? a : 0.f;  // reuse red[] as z2
    }
    __syncthreads();

    if (t == 0) {
        float a = fc2b[0];
        for (int k = 0; k < 32; ++k) a += red[k] * fc2w[k];
        out[g] = a;
    }
}

// ---------------------------------------------------------------------------
extern "C" void kernel_launch(void* const* d_in, const int* in_sizes, int n_in,
                              void* d_out, int out_size, void* d_ws, size_t ws_size,
                              hipStream_t stream)
{
    const float* x         = (const float*)d_in[0];
    const float* ea        = (const float*)d_in[1];
    const float* ratios    = (const float*)d_in[2];
    const int*   eidx      = (const int*)  d_in[3];
    const int*   batch     = (const int*)  d_in[4];
    const int*   ids       = (const int*)  d_in[5];
    const float* W1        = (const float*)d_in[6];
    const float* b1        = (const float*)d_in[7];
    const float* W2        = (const float*)d_in[8];
    const float* b2        = (const float*)d_in[9];
    const float* emb       = (const float*)d_in[10];
    const float* root      = (const float*)d_in[11];
    const float* conv_bias = (const float*)d_in[12];
    const float* fc0w      = (const float*)d_in[13];
    const float* fc0b      = (const float*)d_in[14];
    const float* fc1w      = (const float*)d_in[15];
    const float* fc1b      = (const float*)d_in[16];
    const float* fc2w      = (const float*)d_in[17];
    const float* fc2b      = (const float*)d_in[18];

    const int N = in_sizes[0] / NODE_DIM;   // 50000
    const int E = in_sizes[1] / 3;          // 1000000
    const int G = out_size;                 // 128

    float* s   = (float*)d_ws;                                   // [N,32]
    int*   cnt = (int*)((char*)d_ws + (size_t)N * 32 * 4);       // [N]
    hipMemsetAsync(d_ws, 0, (size_t)N * 32 * 4 + (size_t)N * 4, stream);

    edge_kernel<<<1024, 256, 0, stream>>>(x, ea, eidx, W1, b1, W2, b2, s, cnt, E);
    node_kernel<<<(N * 32 + 255) / 256, 256, 0, stream>>>(x, root, conv_bias, s, cnt, N);
    pool_mlp_kernel<<<G, 128, 0, stream>>>(s, batch, ratios, ids, emb,
                                           fc0w, fc0b, fc1w, fc1b, fc2w, fc2b,
                                           (float*)d_out, N);
}